// Round 12
// baseline (572.783 us; speedup 1.0000x reference)
//
#include <hip/hip_runtime.h>
#include <hip/hip_bf16.h>

// Attention_88270167868034: N=8192, D=256
//   value = x@Vw.T + Vb ; scores = x@x.T/16 masked by adj ; p = softmax ; Vs = p@value
// Design: no-max softmax (scores bounded ~23 by Cauchy-Schwarz), e=exp(s)*mask stored
// bf16 in ws. adj packed to 1-bit bitmap (268MB -> 8.4MB) by k_prep_adj.
// pass1 = barrier-free (B-tile staged once; waves free-run 16 row-iters with issue-early
// A/mask prefetch; A re-reads are L2 hits now that the adj stream is gone).
// k_vs = LDS-staged GEMM. k_norm = stream.
// ws: xb(4MB) | vT(4MB) | rl(32KB @8MB) | lpart/vspb union(@11MB,16MB) | ews(@27MB,128MB) |
//     adjp(8.4MB @156MB).  lpart (128x8192 f32 = 4MB) aliases vspb: dead before k_vs.
// NOTE: __builtin_nontemporal_* requires clang ext_vector types, NOT HIP_vector_type.

#define NN 8192
#define DD 256

typedef __attribute__((ext_vector_type(8))) short bf16x8;
typedef __attribute__((ext_vector_type(8))) unsigned short u16x8;
typedef __attribute__((ext_vector_type(4))) float f32x4;
typedef __attribute__((ext_vector_type(4))) int i32x4;

__device__ __forceinline__ unsigned short f2bf(float f) {
  unsigned u = __builtin_bit_cast(unsigned, f);
  u += 0x7fffu + ((u >> 16) & 1u);
  return (unsigned short)(u >> 16);
}
__device__ __forceinline__ float bf2f(unsigned short h) {
  unsigned u = ((unsigned)h) << 16;
  return __builtin_bit_cast(float, u);
}
__device__ __forceinline__ unsigned pack2(float a, float b) {
  return (unsigned)f2bf(a) | ((unsigned)f2bf(b) << 16);
}

// ---------------- x -> bf16 (plain row-major) ----------------
__global__ void k_prep_x(const float* __restrict__ x, unsigned short* __restrict__ xb) {
  int t = blockIdx.x * 256 + threadIdx.x;              // 262144 threads, 8 elems each
  const float4* s = reinterpret_cast<const float4*>(x) + (size_t)t * 2;
  float4 f0 = s[0], f1 = s[1];
  uint4 o;
  o.x = pack2(f0.x, f0.y); o.y = pack2(f0.z, f0.w);
  o.z = pack2(f1.x, f1.y); o.w = pack2(f1.z, f1.w);
  reinterpret_cast<uint4*>(xb)[t] = o;
}

// ---------------- adj int32 -> 1-bit bitmap (row-major, bit j of byte b = col b*8+j) ----
__global__ void k_prep_adj(const int* __restrict__ adj, unsigned char* __restrict__ adjp) {
  size_t t = (size_t)blockIdx.x * 256 + threadIdx.x;   // 8,388,608 threads, 8 ints -> 1 byte
  const i32x4* s = reinterpret_cast<const i32x4*>(adj) + t * 2;
  i32x4 v0 = __builtin_nontemporal_load(s);
  i32x4 v1 = __builtin_nontemporal_load(s + 1);
  unsigned b = 0;
  b |= (v0[0] != 0) ? 1u : 0u;  b |= (v0[1] != 0) ? 2u : 0u;
  b |= (v0[2] != 0) ? 4u : 0u;  b |= (v0[3] != 0) ? 8u : 0u;
  b |= (v1[0] != 0) ? 16u : 0u; b |= (v1[1] != 0) ? 32u : 0u;
  b |= (v1[2] != 0) ? 64u : 0u; b |= (v1[3] != 0) ? 128u : 0u;
  adjp[t] = (unsigned char)b;
}

// ---------------- value^T = (x@Vw.T + Vb)^T in bf16: vT[n][m] ----------------
// grid 512: mb=bid>>2 (64 rows of m each), nb=bid&3 (64 cols of n each); 256 thr, 4 waves
__global__ __launch_bounds__(256) void k_value(
    const float* __restrict__ Vw, const float* __restrict__ Vb,
    const unsigned short* __restrict__ xb, unsigned short* __restrict__ vT) {
  __shared__ unsigned short lB[64 * 256];              // [n][k] swizzled, 512B rows, 32KB
  int mb = blockIdx.x >> 2, nb = blockIdx.x & 3;
  int tid = threadIdx.x, lane = tid & 63, w = tid >> 6;
  int mw = w >> 1, nw = w & 1;
  // stage B = Vw rows (B[k][n] = Vw[n][k]), cvt f32->bf16
  {
    int n_l = tid >> 2, q = tid & 3;
#pragma unroll
    for (int o = 0; o < 8; ++o) {
      int k0 = q * 64 + o * 8;
      const float4* src = reinterpret_cast<const float4*>(Vw + (nb * 64 + n_l) * DD + k0);
      float4 g0 = src[0], g1 = src[1];
      uint4 pk;
      pk.x = pack2(g0.x, g0.y); pk.y = pack2(g0.z, g0.w);
      pk.z = pack2(g1.x, g1.y); pk.w = pack2(g1.z, g1.w);
      *reinterpret_cast<uint4*>(reinterpret_cast<char*>(lB) + n_l * 512 + ((k0 * 2) ^ ((n_l & 7) << 4))) = pk;
    }
  }
  // A (x rows) directly into registers from L2-resident xb
  bf16x8 aR[2][8];
#pragma unroll
  for (int mf = 0; mf < 2; ++mf) {
    int rg = mb * 64 + mw * 32 + mf * 16 + (lane & 15);
    const char* base = reinterpret_cast<const char*>(xb + (size_t)rg * DD);
#pragma unroll
    for (int ks = 0; ks < 8; ++ks)
      aR[mf][ks] = *reinterpret_cast<const bf16x8*>(base + ks * 64 + ((lane >> 4) * 16));
  }
  __syncthreads();
  f32x4 acc[2][2] = {};
#pragma unroll
  for (int ks = 0; ks < 8; ++ks) {
    int kb = ks * 64 + ((lane >> 4) * 16);
#pragma unroll
    for (int nf = 0; nf < 2; ++nf) {
      int n = nw * 32 + nf * 16 + (lane & 15);
      bf16x8 b = *reinterpret_cast<const bf16x8*>(reinterpret_cast<const char*>(lB) + n * 512 + (kb ^ ((n & 7) << 4)));
#pragma unroll
      for (int mf = 0; mf < 2; ++mf)
        acc[mf][nf] = __builtin_amdgcn_mfma_f32_16x16x32_bf16(aR[mf][ks], b, acc[mf][nf], 0, 0, 0);
    }
  }
#pragma unroll
  for (int nf = 0; nf < 2; ++nf) {
    int n_g = nb * 64 + nw * 32 + nf * 16 + (lane & 15);
    float vb = Vb[n_g];
#pragma unroll
    for (int mf = 0; mf < 2; ++mf) {
      int m_g = mb * 64 + mw * 32 + mf * 16 + ((lane >> 4) << 2);
      ushort4 h;
      h.x = f2bf(acc[mf][nf][0] + vb);
      h.y = f2bf(acc[mf][nf][1] + vb);
      h.z = f2bf(acc[mf][nf][2] + vb);
      h.w = f2bf(acc[mf][nf][3] + vb);
      *reinterpret_cast<ushort4*>(vT + (size_t)n_g * NN + m_g) = h;
    }
  }
}

// ---------------- pass1: e = exp(x@x.T/16)*mask -> ews (bf16), row sums ----------------
// Barrier-free: grid 1024 = 128 cb (64 cols) x 8 rs (1024-row strip); 256 thr = 4 waves.
// B-tile (64 key rows, 32KB swizzled) staged ONCE, one barrier; then each wave free-runs
// 16 iters x 16 rows with ISSUE-EARLY prefetch of next iter's A-frags + mask words.
// A re-reads hit L2 (xb 4MB + adjp 8.4MB resident; no adj stream to evict them).
__global__ __launch_bounds__(256, 4) void k_pass1(
    const unsigned short* __restrict__ xb, const unsigned long long* __restrict__ adjp,
    unsigned short* __restrict__ ews, float* __restrict__ lpart) {
  __shared__ char lB[32768];                           // [64 cols][512B] swizzled
  int cb = blockIdx.x & 127, rs = blockIdx.x >> 7;
  int tid = threadIdx.x, lane = tid & 63, w = tid >> 6;
  int ln = lane & 15, kq = lane >> 4;
  // stage B tile once (key rows cb*64..+63)
#pragma unroll
  for (int q = 0; q < 8; ++q) {
    int id = q * 256 + tid, col = id >> 5, oct = id & 31;
    uint4 v = *reinterpret_cast<const uint4*>(xb + (size_t)(cb * 64 + col) * DD + oct * 8);
    *reinterpret_cast<uint4*>(&lB[col * 512 + ((oct * 16) ^ ((col & 7) << 4))]) = v;
  }
  __syncthreads();
  int c0 = cb * 64 + ln;                               // + nf*16 per fragment

#define LOADA(A, IT)                                                                    \
  {                                                                                     \
    const char* ab_ = reinterpret_cast<const char*>(                                    \
        xb + (size_t)(rs * 1024 + (IT) * 64 + w * 16 + ln) * DD);                       \
    _Pragma("unroll") for (int ks_ = 0; ks_ < 8; ++ks_)                                 \
      (A)[ks_] = *reinterpret_cast<const bf16x8*>(ab_ + ks_ * 64 + kq * 16);            \
  }
#define LOADM(M, IT)                                                                    \
  {                                                                                     \
    int rm_ = rs * 1024 + (IT) * 64 + w * 16 + kq * 4;                                  \
    _Pragma("unroll") for (int i_ = 0; i_ < 4; ++i_)                                    \
      (M)[i_] = adjp[(size_t)(rm_ + i_) * 128 + cb];                                    \
  }

  bf16x8 aC[8], aN[8];
  unsigned long long mC[4], mN[4];
  LOADA(aC, 0);
  LOADM(mC, 0);

  for (int it = 0; it < 16; ++it) {
    bool has = it < 15;
    if (has) {
      LOADA(aN, it + 1);                               // issue-early: in flight during MFMA
      LOADM(mN, it + 1);
    }
    f32x4 acc[4] = {};
#pragma unroll
    for (int ks = 0; ks < 8; ++ks) {
      int kb = ks * 64 + kq * 16;
#pragma unroll
      for (int nf = 0; nf < 4; ++nf) {
        int cc = nf * 16 + ln;
        bf16x8 b = *reinterpret_cast<const bf16x8*>(&lB[cc * 512 + (kb ^ ((cc & 7) << 4))]);
        acc[nf] = __builtin_amdgcn_mfma_f32_16x16x32_bf16(aC[ks], b, acc[nf], 0, 0, 0);
      }
    }
    // epilogue: masked exp, bf16 store, rowsum of rounded values
    int r0 = rs * 1024 + it * 64 + w * 16 + kq * 4;
    float rsum[4] = {};
#pragma unroll
    for (int nf = 0; nf < 4; ++nf)
#pragma unroll
      for (int i = 0; i < 4; ++i) {
        bool on = (mC[i] >> (nf * 16 + ln)) & 1;
        float e = on ? __expf(acc[nf][i] * 0.0625f) : 0.f;
        unsigned short h = f2bf(e);
        ews[(size_t)(r0 + i) * NN + c0 + nf * 16] = h;
        rsum[i] += bf2f(h);
      }
    // 16-lane shuffle reduce over cols -> complete row sums for this col-block
#pragma unroll
    for (int i = 0; i < 4; ++i) {
      float r = rsum[i];
      r += __shfl_xor(r, 1); r += __shfl_xor(r, 2);
      r += __shfl_xor(r, 4); r += __shfl_xor(r, 8);
      if (ln == 0) lpart[(size_t)cb * NN + r0 + i] = r;
    }
#pragma unroll
    for (int s = 0; s < 8; ++s) aC[s] = aN[s];
#pragma unroll
    for (int i = 0; i < 4; ++i) mC[i] = mN[i];
  }
#undef LOADA
#undef LOADM
}

// ---------------- rl = 1/rowsum ----------------
__global__ void k_reduce_l(const float* __restrict__ lpart, float* __restrict__ rl) {
  int i = blockIdx.x * 256 + threadIdx.x;              // 8192
  float s = 0.f;
  for (int c = 0; c < 128; ++c) s += lpart[(size_t)c * NN + i];
  rl[i] = s > 0.f ? 1.f / s : 0.f;
}

// ---------------- k_vs: Vs-partial = (e @ value) * rl, LDS-staged B ----------------
// grid 256 = 64 rt (128 rows) x 4 ck (splitK 2048); 512 thr = 8 waves, wave = 16 rows x 256 n.
// B chunk [256n][128k] = 64KB, double-buffered (128KB LDS). Per chunk: issue next B+A ->
// 64 MFMA -> ds-write next -> 1 barrier. 16 chunks. A (ews) nontemporal.
__global__ __launch_bounds__(512) void k_vs(
    const unsigned short* __restrict__ ews, const unsigned short* __restrict__ vT,
    const float* __restrict__ rl, unsigned short* __restrict__ vspb) {
  __shared__ char lV[2][65536];                        // [n=256][k=128] bf16, 256B rows, XOR swizzled
  int rt = blockIdx.x >> 2, ck = blockIdx.x & 3;
  int tid = threadIdx.x, lane = tid & 63, w = tid >> 6;
  int ln = lane & 15, kq = lane >> 4;
  int row = rt * 128 + w * 16 + ln;
  const unsigned short* ap = ews + (size_t)row * NN + ck * 2048 + kq * 8;

#define LOADB(G, KC)                                                                     \
  _Pragma("unroll") for (int q = 0; q < 8; ++q) {                                        \
    int id_ = q * 512 + tid, n_ = id_ >> 4, o_ = id_ & 15;                               \
    (G)[q] = *reinterpret_cast<const uint4*>(vT + (size_t)n_ * NN + ck * 2048 + (KC) * 128 + o_ * 8); \
  }
#define DSWRITE(G, BB)                                                                   \
  _Pragma("unroll") for (int q = 0; q < 8; ++q) {                                        \
    int id_ = q * 512 + tid, n_ = id_ >> 4, o_ = id_ & 15;                               \
    *reinterpret_cast<uint4*>(&lV[BB][n_ * 256 + ((o_ * 16) ^ ((n_ & 7) << 4))]) = (G)[q]; \
  }
#define LOADA(A, KC)                                                                     \
  _Pragma("unroll") for (int s_ = 0; s_ < 4; ++s_)                                       \
    (A)[s_] = __builtin_nontemporal_load(reinterpret_cast<const bf16x8*>(ap + (KC) * 128 + s_ * 32));

  uint4 gB[8];
  bf16x8 aC[4], aN[4];
  LOADB(gB, 0);
  LOADA(aC, 0);
  DSWRITE(gB, 0);
  __syncthreads();

  f32x4 acc[16] = {};
  for (int kc = 0; kc < 16; ++kc) {
    bool has = kc < 15;
    if (has) {
      LOADB(gB, kc + 1);                               // issue-early: lands during MFMA phase
      LOADA(aN, kc + 1);
    }
    const char* bufc = lV[kc & 1];
#pragma unroll
    for (int ks = 0; ks < 4; ++ks) {
#pragma unroll
      for (int nf = 0; nf < 16; ++nf) {
        int n = nf * 16 + ln;
        bf16x8 b = *reinterpret_cast<const bf16x8*>(bufc + n * 256 + ((ks * 64 + kq * 16) ^ ((n & 7) << 4)));
        acc[nf] = __builtin_amdgcn_mfma_f32_16x16x32_bf16(aC[ks], b, acc[nf], 0, 0, 0);
      }
    }
    if (has) DSWRITE(gB, (kc + 1) & 1);                // write-late into other buffer
    __syncthreads();
#pragma unroll
    for (int s = 0; s < 4; ++s) aC[s] = aN[s];
  }

  // epilogue: normalized bf16 partial for this ck
  int rowo = rt * 128 + w * 16 + kq * 4;
#pragma unroll
  for (int i = 0; i < 4; ++i) {
    float rli = rl[rowo + i];
#pragma unroll
    for (int nf = 0; nf < 16; ++nf) {
      int n = nf * 16 + ln;
      vspb[((size_t)ck * NN + rowo + i) * DD + n] = f2bf(acc[nf][i] * rli);
    }
  }
#undef LOADB
#undef DSWRITE
#undef LOADA
}

// ---------------- k_norm: p = e * rl (streaming, nontemporal in+out) ----------------
__global__ void k_norm(const unsigned short* __restrict__ ews, const float* __restrict__ rl,
                       float* __restrict__ pout) {
  size_t t = (size_t)blockIdx.x * 256 + threadIdx.x;   // 8,388,608 threads, 8 elems each
  float r = rl[t >> 10];
  u16x8 v = __builtin_nontemporal_load(reinterpret_cast<const u16x8*>(ews + t * 8));
  f32x4 o0, o1;
  o0[0] = bf2f(v[0]) * r; o0[1] = bf2f(v[1]) * r; o0[2] = bf2f(v[2]) * r; o0[3] = bf2f(v[3]) * r;
  o1[0] = bf2f(v[4]) * r; o1[1] = bf2f(v[5]) * r; o1[2] = bf2f(v[6]) * r; o1[3] = bf2f(v[7]) * r;
  f32x4* pd = reinterpret_cast<f32x4*>(pout + t * 8);
  __builtin_nontemporal_store(o0, pd);
  __builtin_nontemporal_store(o1, pd + 1);
}

// ---------------- Vs = sum of 4 bf16 split-K partials ----------------
__global__ void k_reduce_vs(const unsigned short* __restrict__ vspb, float* __restrict__ vout) {
  int t = blockIdx.x * 256 + threadIdx.x;              // 262144 threads, 8 outputs each
  float s[8] = {};
#pragma unroll
  for (int c = 0; c < 4; ++c) {
    u16x8 v = *reinterpret_cast<const u16x8*>(vspb + (size_t)c * NN * DD + (size_t)t * 8);
#pragma unroll
    for (int j = 0; j < 8; ++j) s[j] += bf2f(v[j]);
  }
  float4 o0, o1;
  o0.x = s[0]; o0.y = s[1]; o0.z = s[2]; o0.w = s[3];
  o1.x = s[4]; o1.y = s[5]; o1.z = s[6]; o1.w = s[7];
  float4* d = reinterpret_cast<float4*>(vout + (size_t)t * 8);
  d[0] = o0; d[1] = o1;
}

extern "C" void kernel_launch(void* const* d_in, const int* in_sizes, int n_in,
                              void* d_out, int out_size, void* d_ws, size_t ws_size,
                              hipStream_t stream) {
  const float* x   = (const float*)d_in[0];
  const int*   adj = (const int*)d_in[1];
  const float* Vw  = (const float*)d_in[2];
  const float* Vb  = (const float*)d_in[3];
  float* out   = (float*)d_out;
  float* vs_out = out;                                  // [8192][256]
  float* p_out  = out + (size_t)NN * DD;                // [8192][8192]
  char* ws = (char*)d_ws;
  unsigned short* xb   = (unsigned short*)(ws);                       // 4MB
  unsigned short* vT   = (unsigned short*)(ws + ((size_t)4  << 20));  // 4MB
  float* rl            = (float*)(ws + ((size_t)8  << 20));           // 32KB
  float* lpart         = (float*)(ws + ((size_t)11 << 20));           // 4MB (aliases vspb; dead before k_vs)
  unsigned short* vspb = (unsigned short*)(ws + ((size_t)11 << 20));  // 16MB (4 x 8192 x 256 bf16)
  unsigned short* ews  = (unsigned short*)(ws + ((size_t)27 << 20));  // 128MB
  unsigned char* adjp  = (unsigned char*)(ws + ((size_t)156 << 20));  // 8.4MB bitmap

  k_prep_x<<<dim3(1024), dim3(256), 0, stream>>>(x, xb);
  k_prep_adj<<<dim3(32768), dim3(256), 0, stream>>>(adj, adjp);
  k_value<<<dim3(512), dim3(256), 0, stream>>>(Vw, Vb, xb, vT);
  k_pass1<<<dim3(1024), dim3(256), 0, stream>>>(xb, (const unsigned long long*)adjp, ews, lpart);
  k_reduce_l<<<dim3(32), dim3(256), 0, stream>>>(lpart, rl);
  k_vs<<<dim3(256), dim3(512), 0, stream>>>(ews, vT, rl, vspb);
  k_norm<<<dim3(32768), dim3(256), 0, stream>>>(ews, rl, p_out);
  k_reduce_vs<<<dim3(1024), dim3(256), 0, stream>>>(vspb, vs_out);
}

// Round 13
// 294.860 us; speedup vs baseline: 1.9426x; 1.9426x over previous
//
#include <hip/hip_runtime.h>
#include <hip/hip_bf16.h>

// Attention_88270167868034: N=8192, D=256
//   value = x@Vw.T + Vb ; scores = x@x.T/16 masked by adj ; p = softmax ; Vs = p@value
// Design: no-max softmax (scores bounded ~23 by Cauchy-Schwarz), e=exp(s)*mask stored
// bf16 in ws. adj packed to 1-bit bitmap (268MB -> 8.4MB) by k_prep_adj.
// pass1 = 8-wave persistent strips (128 rows x 1024 cols), dbuf B chunks, 1 barrier/chunk
//         (R11 structure — best measured; barrier-free variants thrash L2 w/ store stream).
// k_vs = LDS-staged GEMM. k_norm = stream.
// ws: xb(4MB) | vT(4MB) | rl(32KB @8MB) | lpart(256KB @9MB) | vspb(16MB @11MB) |
//     ews(128MB @27MB) | adjp(8.4MB @156MB)
// NOTE: __builtin_nontemporal_* requires clang ext_vector types, NOT HIP_vector_type.

#define NN 8192
#define DD 256

typedef __attribute__((ext_vector_type(8))) short bf16x8;
typedef __attribute__((ext_vector_type(8))) unsigned short u16x8;
typedef __attribute__((ext_vector_type(4))) float f32x4;
typedef __attribute__((ext_vector_type(4))) int i32x4;

__device__ __forceinline__ unsigned short f2bf(float f) {
  unsigned u = __builtin_bit_cast(unsigned, f);
  u += 0x7fffu + ((u >> 16) & 1u);
  return (unsigned short)(u >> 16);
}
__device__ __forceinline__ float bf2f(unsigned short h) {
  unsigned u = ((unsigned)h) << 16;
  return __builtin_bit_cast(float, u);
}
__device__ __forceinline__ unsigned pack2(float a, float b) {
  return (unsigned)f2bf(a) | ((unsigned)f2bf(b) << 16);
}

// ---------------- x -> bf16 (plain row-major) ----------------
__global__ void k_prep_x(const float* __restrict__ x, unsigned short* __restrict__ xb) {
  int t = blockIdx.x * 256 + threadIdx.x;              // 262144 threads, 8 elems each
  const float4* s = reinterpret_cast<const float4*>(x) + (size_t)t * 2;
  float4 f0 = s[0], f1 = s[1];
  uint4 o;
  o.x = pack2(f0.x, f0.y); o.y = pack2(f0.z, f0.w);
  o.z = pack2(f1.x, f1.y); o.w = pack2(f1.z, f1.w);
  reinterpret_cast<uint4*>(xb)[t] = o;
}

// ---------------- adj int32 -> 1-bit bitmap (row-major, bit j of byte b = col b*8+j) ----
__global__ void k_prep_adj(const int* __restrict__ adj, unsigned char* __restrict__ adjp) {
  size_t t = (size_t)blockIdx.x * 256 + threadIdx.x;   // 8,388,608 threads, 8 ints -> 1 byte
  const i32x4* s = reinterpret_cast<const i32x4*>(adj) + t * 2;
  i32x4 v0 = __builtin_nontemporal_load(s);
  i32x4 v1 = __builtin_nontemporal_load(s + 1);
  unsigned b = 0;
  b |= (v0[0] != 0) ? 1u : 0u;  b |= (v0[1] != 0) ? 2u : 0u;
  b |= (v0[2] != 0) ? 4u : 0u;  b |= (v0[3] != 0) ? 8u : 0u;
  b |= (v1[0] != 0) ? 16u : 0u; b |= (v1[1] != 0) ? 32u : 0u;
  b |= (v1[2] != 0) ? 64u : 0u; b |= (v1[3] != 0) ? 128u : 0u;
  adjp[t] = (unsigned char)b;
}

// ---------------- value^T = (x@Vw.T + Vb)^T in bf16: vT[n][m] ----------------
// grid 512: mb=bid>>2 (64 rows of m each), nb=bid&3 (64 cols of n each); 256 thr, 4 waves
__global__ __launch_bounds__(256) void k_value(
    const float* __restrict__ Vw, const float* __restrict__ Vb,
    const unsigned short* __restrict__ xb, unsigned short* __restrict__ vT) {
  __shared__ unsigned short lB[64 * 256];              // [n][k] swizzled, 512B rows, 32KB
  int mb = blockIdx.x >> 2, nb = blockIdx.x & 3;
  int tid = threadIdx.x, lane = tid & 63, w = tid >> 6;
  int mw = w >> 1, nw = w & 1;
  // stage B = Vw rows (B[k][n] = Vw[n][k]), cvt f32->bf16
  {
    int n_l = tid >> 2, q = tid & 3;
#pragma unroll
    for (int o = 0; o < 8; ++o) {
      int k0 = q * 64 + o * 8;
      const float4* src = reinterpret_cast<const float4*>(Vw + (nb * 64 + n_l) * DD + k0);
      float4 g0 = src[0], g1 = src[1];
      uint4 pk;
      pk.x = pack2(g0.x, g0.y); pk.y = pack2(g0.z, g0.w);
      pk.z = pack2(g1.x, g1.y); pk.w = pack2(g1.z, g1.w);
      *reinterpret_cast<uint4*>(reinterpret_cast<char*>(lB) + n_l * 512 + ((k0 * 2) ^ ((n_l & 7) << 4))) = pk;
    }
  }
  // A (x rows) directly into registers from L2-resident xb
  bf16x8 aR[2][8];
#pragma unroll
  for (int mf = 0; mf < 2; ++mf) {
    int rg = mb * 64 + mw * 32 + mf * 16 + (lane & 15);
    const char* base = reinterpret_cast<const char*>(xb + (size_t)rg * DD);
#pragma unroll
    for (int ks = 0; ks < 8; ++ks)
      aR[mf][ks] = *reinterpret_cast<const bf16x8*>(base + ks * 64 + ((lane >> 4) * 16));
  }
  __syncthreads();
  f32x4 acc[2][2] = {};
#pragma unroll
  for (int ks = 0; ks < 8; ++ks) {
    int kb = ks * 64 + ((lane >> 4) * 16);
#pragma unroll
    for (int nf = 0; nf < 2; ++nf) {
      int n = nw * 32 + nf * 16 + (lane & 15);
      bf16x8 b = *reinterpret_cast<const bf16x8*>(reinterpret_cast<const char*>(lB) + n * 512 + (kb ^ ((n & 7) << 4)));
#pragma unroll
      for (int mf = 0; mf < 2; ++mf)
        acc[mf][nf] = __builtin_amdgcn_mfma_f32_16x16x32_bf16(aR[mf][ks], b, acc[mf][nf], 0, 0, 0);
    }
  }
#pragma unroll
  for (int nf = 0; nf < 2; ++nf) {
    int n_g = nb * 64 + nw * 32 + nf * 16 + (lane & 15);
    float vb = Vb[n_g];
#pragma unroll
    for (int mf = 0; mf < 2; ++mf) {
      int m_g = mb * 64 + mw * 32 + mf * 16 + ((lane >> 4) << 2);
      ushort4 h;
      h.x = f2bf(acc[mf][nf][0] + vb);
      h.y = f2bf(acc[mf][nf][1] + vb);
      h.z = f2bf(acc[mf][nf][2] + vb);
      h.w = f2bf(acc[mf][nf][3] + vb);
      *reinterpret_cast<ushort4*>(vT + (size_t)n_g * NN + m_g) = h;
    }
  }
}

// ---------------- pass1: e = exp(x@x.T/16)*mask -> ews (bf16), row sums ----------------
// 8-wave persistent strips: grid 512 = 8 cs (1024-col strip) x 64 rb (128 rows), cs-major.
// Per block: A (128 rows x 256k) in regs once; 16 chunks of 64 cols; B chunk [64][512B]
// dbuf (64KB LDS -> 2 blocks/CU = 16 waves/CU); issue-early next-B, mask u64 broadcast
// at chunk start (hidden under MFMA), 1 barrier/chunk; rowsums in regs -> lpart[cs].
__global__ __launch_bounds__(512, 4) void k_pass1(
    const unsigned short* __restrict__ xb, const unsigned long long* __restrict__ adjp,
    unsigned short* __restrict__ ews, float* __restrict__ lpart) {
  __shared__ char lB[2][32768];                        // [64 cols][512B] swizzled
  int cs = blockIdx.x >> 6, rb = blockIdx.x & 63;
  int tid = threadIdx.x, lane = tid & 63, w = tid >> 6;
  int ln = lane & 15, kq = lane >> 4;
  int colb = cs * 1024;
  int r0 = rb * 128 + w * 16 + (kq << 2);              // this lane's 4 acc rows

  // A (query rows) into registers: wave w owns rows rb*128 + w*16 .. +15
  bf16x8 aR[8];
  {
    const char* abase = reinterpret_cast<const char*>(xb + (size_t)(rb * 128 + w * 16 + ln) * DD);
#pragma unroll
    for (int ks = 0; ks < 8; ++ks)
      aR[ks] = *reinterpret_cast<const bf16x8*>(abase + ks * 64 + kq * 16);
  }

  // B stage: 2048 segs of 16B; thread covers 4: id=q*512+tid -> col=id>>5, oct=id&31
#define LOADB(G, KC)                                                                   \
  _Pragma("unroll") for (int q = 0; q < 4; ++q) {                                      \
    int id_ = q * 512 + tid, col_ = id_ >> 5, oct_ = id_ & 31;                         \
    (G)[q] = *reinterpret_cast<const uint4*>(xb + (size_t)(colb + (KC) * 64 + col_) * DD + oct_ * 8); \
  }
#define DSWRITE(G, BB)                                                                 \
  _Pragma("unroll") for (int q = 0; q < 4; ++q) {                                      \
    int id_ = q * 512 + tid, col_ = id_ >> 5, oct_ = id_ & 31;                         \
    *reinterpret_cast<uint4*>(&lB[BB][col_ * 512 + ((oct_ * 16) ^ ((col_ & 7) << 4))]) = (G)[q]; \
  }

  uint4 gB[4];
  LOADB(gB, 0);
  DSWRITE(gB, 0);
  __syncthreads();

  float rsum[4] = {};
  for (int kc = 0; kc < 16; ++kc) {
    bool has = kc < 15;
    if (has) LOADB(gB, kc + 1);                        // issue-early: lands during MFMA
    // mask words for this chunk (broadcast u64, L2-hot; consumed after 32 MFMA)
    unsigned long long m[4];
#pragma unroll
    for (int i = 0; i < 4; ++i)
      m[i] = adjp[(size_t)(r0 + i) * 128 + cs * 16 + kc];
    const char* bufc = lB[kc & 1];
    f32x4 acc[4] = {};
    __builtin_amdgcn_s_setprio(1);                     // T5: favor MFMA-entering waves
#pragma unroll
    for (int ks = 0; ks < 8; ++ks) {
      int kb = ks * 64 + kq * 16;
#pragma unroll
      for (int nf = 0; nf < 4; ++nf) {
        int cc = nf * 16 + ln;
        bf16x8 b = *reinterpret_cast<const bf16x8*>(bufc + cc * 512 + (kb ^ ((cc & 7) << 4)));
        acc[nf] = __builtin_amdgcn_mfma_f32_16x16x32_bf16(aR[ks], b, acc[nf], 0, 0, 0);
      }
    }
    __builtin_amdgcn_s_setprio(0);
    // epilogue: masked exp, bf16 store; rowsum of UNROUNDED e (threshold headroom 3.5x)
    int c0 = colb + kc * 64 + ln;
#pragma unroll
    for (int nf = 0; nf < 4; ++nf)
#pragma unroll
      for (int i = 0; i < 4; ++i) {
        bool on = (m[i] >> (nf * 16 + ln)) & 1;
        float e = on ? __expf(acc[nf][i] * 0.0625f) : 0.f;
        ews[(size_t)(r0 + i) * NN + c0 + nf * 16] = f2bf(e);
        rsum[i] += e;
      }
    if (has) DSWRITE(gB, (kc + 1) & 1);                // write-late into other buffer
    __syncthreads();
  }
  // 16-lane shuffle reduce over cols -> strip row sums
#pragma unroll
  for (int i = 0; i < 4; ++i) {
    float r = rsum[i];
    r += __shfl_xor(r, 1); r += __shfl_xor(r, 2);
    r += __shfl_xor(r, 4); r += __shfl_xor(r, 8);
    if (ln == 0) lpart[(size_t)cs * NN + r0 + i] = r;
  }
#undef LOADB
#undef DSWRITE
}

// ---------------- rl = 1/rowsum ----------------
__global__ void k_reduce_l(const float* __restrict__ lpart, float* __restrict__ rl) {
  int i = blockIdx.x * 256 + threadIdx.x;              // 8192
  float s = 0.f;
  for (int c = 0; c < 8; ++c) s += lpart[(size_t)c * NN + i];
  rl[i] = s > 0.f ? 1.f / s : 0.f;
}

// ---------------- k_vs: Vs-partial = (e @ value) * rl, LDS-staged B ----------------
// grid 256 = 64 rt (128 rows) x 4 ck (splitK 2048); 512 thr = 8 waves, wave = 16 rows x 256 n.
// B chunk [256n][128k] = 64KB, double-buffered (128KB LDS). Per chunk: issue next B+A ->
// 64 MFMA -> ds-write next -> 1 barrier. 16 chunks. A (ews) nontemporal.
__global__ __launch_bounds__(512) void k_vs(
    const unsigned short* __restrict__ ews, const unsigned short* __restrict__ vT,
    const float* __restrict__ rl, unsigned short* __restrict__ vspb) {
  __shared__ char lV[2][65536];                        // [n=256][k=128] bf16, 256B rows, XOR swizzled
  int rt = blockIdx.x >> 2, ck = blockIdx.x & 3;
  int tid = threadIdx.x, lane = tid & 63, w = tid >> 6;
  int ln = lane & 15, kq = lane >> 4;
  int row = rt * 128 + w * 16 + ln;
  const unsigned short* ap = ews + (size_t)row * NN + ck * 2048 + kq * 8;

#define LOADB(G, KC)                                                                     \
  _Pragma("unroll") for (int q = 0; q < 8; ++q) {                                        \
    int id_ = q * 512 + tid, n_ = id_ >> 4, o_ = id_ & 15;                               \
    (G)[q] = *reinterpret_cast<const uint4*>(vT + (size_t)n_ * NN + ck * 2048 + (KC) * 128 + o_ * 8); \
  }
#define DSWRITE(G, BB)                                                                   \
  _Pragma("unroll") for (int q = 0; q < 8; ++q) {                                        \
    int id_ = q * 512 + tid, n_ = id_ >> 4, o_ = id_ & 15;                               \
    *reinterpret_cast<uint4*>(&lV[BB][n_ * 256 + ((o_ * 16) ^ ((n_ & 7) << 4))]) = (G)[q]; \
  }
#define LOADA(A, KC)                                                                     \
  _Pragma("unroll") for (int s_ = 0; s_ < 4; ++s_)                                       \
    (A)[s_] = __builtin_nontemporal_load(reinterpret_cast<const bf16x8*>(ap + (KC) * 128 + s_ * 32));

  uint4 gB[8];
  bf16x8 aC[4], aN[4];
  LOADB(gB, 0);
  LOADA(aC, 0);
  DSWRITE(gB, 0);
  __syncthreads();

  f32x4 acc[16] = {};
  for (int kc = 0; kc < 16; ++kc) {
    bool has = kc < 15;
    if (has) {
      LOADB(gB, kc + 1);                               // issue-early: lands during MFMA phase
      LOADA(aN, kc + 1);
    }
    const char* bufc = lV[kc & 1];
    __builtin_amdgcn_s_setprio(1);                     // T5
#pragma unroll
    for (int ks = 0; ks < 4; ++ks) {
#pragma unroll
      for (int nf = 0; nf < 16; ++nf) {
        int n = nf * 16 + ln;
        bf16x8 b = *reinterpret_cast<const bf16x8*>(bufc + n * 256 + ((ks * 64 + kq * 16) ^ ((n & 7) << 4)));
        acc[nf] = __builtin_amdgcn_mfma_f32_16x16x32_bf16(aC[ks], b, acc[nf], 0, 0, 0);
      }
    }
    __builtin_amdgcn_s_setprio(0);
    if (has) DSWRITE(gB, (kc + 1) & 1);                // write-late into other buffer
    __syncthreads();
#pragma unroll
    for (int s = 0; s < 4; ++s) aC[s] = aN[s];
  }

  // epilogue: normalized bf16 partial for this ck
  int rowo = rt * 128 + w * 16 + kq * 4;
#pragma unroll
  for (int i = 0; i < 4; ++i) {
    float rli = rl[rowo + i];
#pragma unroll
    for (int nf = 0; nf < 16; ++nf) {
      int n = nf * 16 + ln;
      vspb[((size_t)ck * NN + rowo + i) * DD + n] = f2bf(acc[nf][i] * rli);
    }
  }
#undef LOADB
#undef DSWRITE
#undef LOADA
}

// ---------------- k_norm: p = e * rl (streaming, nontemporal in+out) ----------------
__global__ void k_norm(const unsigned short* __restrict__ ews, const float* __restrict__ rl,
                       float* __restrict__ pout) {
  size_t t = (size_t)blockIdx.x * 256 + threadIdx.x;   // 8,388,608 threads, 8 elems each
  float r = rl[t >> 10];
  u16x8 v = __builtin_nontemporal_load(reinterpret_cast<const u16x8*>(ews + t * 8));
  f32x4 o0, o1;
  o0[0] = bf2f(v[0]) * r; o0[1] = bf2f(v[1]) * r; o0[2] = bf2f(v[2]) * r; o0[3] = bf2f(v[3]) * r;
  o1[0] = bf2f(v[4]) * r; o1[1] = bf2f(v[5]) * r; o1[2] = bf2f(v[6]) * r; o1[3] = bf2f(v[7]) * r;
  f32x4* pd = reinterpret_cast<f32x4*>(pout + t * 8);
  __builtin_nontemporal_store(o0, pd);
  __builtin_nontemporal_store(o1, pd + 1);
}

// ---------------- Vs = sum of 4 bf16 split-K partials ----------------
__global__ void k_reduce_vs(const unsigned short* __restrict__ vspb, float* __restrict__ vout) {
  int t = blockIdx.x * 256 + threadIdx.x;              // 262144 threads, 8 outputs each
  float s[8] = {};
#pragma unroll
  for (int c = 0; c < 4; ++c) {
    u16x8 v = *reinterpret_cast<const u16x8*>(vspb + (size_t)c * NN * DD + (size_t)t * 8);
#pragma unroll
    for (int j = 0; j < 8; ++j) s[j] += bf2f(v[j]);
  }
  float4 o0, o1;
  o0.x = s[0]; o0.y = s[1]; o0.z = s[2]; o0.w = s[3];
  o1.x = s[4]; o1.y = s[5]; o1.z = s[6]; o1.w = s[7];
  float4* d = reinterpret_cast<float4*>(vout + (size_t)t * 8);
  d[0] = o0; d[1] = o1;
}

extern "C" void kernel_launch(void* const* d_in, const int* in_sizes, int n_in,
                              void* d_out, int out_size, void* d_ws, size_t ws_size,
                              hipStream_t stream) {
  const float* x   = (const float*)d_in[0];
  const int*   adj = (const int*)d_in[1];
  const float* Vw  = (const float*)d_in[2];
  const float* Vb  = (const float*)d_in[3];
  float* out   = (float*)d_out;
  float* vs_out = out;                                  // [8192][256]
  float* p_out  = out + (size_t)NN * DD;                // [8192][8192]
  char* ws = (char*)d_ws;
  unsigned short* xb   = (unsigned short*)(ws);                       // 4MB
  unsigned short* vT   = (unsigned short*)(ws + ((size_t)4  << 20));  // 4MB
  float* rl            = (float*)(ws + ((size_t)8  << 20));           // 32KB
  float* lpart         = (float*)(ws + ((size_t)9  << 20));           // 256KB (8 x 8192 f32)
  unsigned short* vspb = (unsigned short*)(ws + ((size_t)11 << 20));  // 16MB (4 x 8192 x 256 bf16)
  unsigned short* ews  = (unsigned short*)(ws + ((size_t)27 << 20));  // 128MB
  unsigned char* adjp  = (unsigned char*)(ws + ((size_t)156 << 20));  // 8.4MB bitmap

  k_prep_x<<<dim3(1024), dim3(256), 0, stream>>>(x, xb);
  k_prep_adj<<<dim3(32768), dim3(256), 0, stream>>>(adj, adjp);
  k_value<<<dim3(512), dim3(256), 0, stream>>>(Vw, Vb, xb, vT);
  k_pass1<<<dim3(512), dim3(512), 0, stream>>>(xb, (const unsigned long long*)adjp, ews, lpart);
  k_reduce_l<<<dim3(32), dim3(256), 0, stream>>>(lpart, rl);
  k_vs<<<dim3(256), dim3(512), 0, stream>>>(ews, vT, rl, vspb);
  k_norm<<<dim3(32768), dim3(256), 0, stream>>>(ews, rl, p_out);
  k_reduce_vs<<<dim3(1024), dim3(256), 0, stream>>>(vspb, vs_out);
}